// Round 7
// baseline (1188.432 us; speedup 1.0000x reference)
//
#include <hip/hip_runtime.h>

#define NBLK 256
#define NTHR 512
#define MTILE 32
#define KPADI 592                // abuf row stride bytes (16-aligned)
#define HSTR  528                // hsave row stride bytes
#define CHB   (9*8*64*16)        // 73728 bytes per 16-col chunk per LSTM (9 k-tiles of K=64)
#define LSTR  (16*CHB)           // 1179648 bytes per LSTM

typedef __attribute__((ext_vector_type(4))) int int4v;

__device__ inline float ex2(float x){ return __builtin_amdgcn_exp2f(x); }
__device__ inline float rcpf_(float d){ return __builtin_amdgcn_rcpf(d); }
__device__ inline float rcpn(float d){ float r=__builtin_amdgcn_rcpf(d); return r*(2.f-d*r); }
#define LOG2E 1.4426950408889634f
__device__ inline float sigf(float x){ return rcpf_(1.f+ex2(-LOG2E*x)); }
__device__ inline float tanh_(float x){ return 2.f*rcpf_(1.f+ex2(-2.f*LOG2E*x))-1.f; }

// 4x int8 dot product (exact integer math; matches the MFMA tile-8 contribution).
__device__ inline int dot4i8(int a, int b){
#if __has_builtin(__builtin_amdgcn_sdot4)
    return __builtin_amdgcn_sdot4(a, b, 0, false);
#else
    return (int)((signed char)(a))      *(int)((signed char)(b))
         + (int)((signed char)(a>>8))   *(int)((signed char)(b>>8))
         + (int)((signed char)(a>>16))  *(int)((signed char)(b>>16))
         + (int)((signed char)(a>>24))  *(int)((signed char)(b>>24));
#endif
}

// Barrier draining only LDS ops (lgkmcnt); global loads stay in flight.
__device__ inline void lbar(){
    asm volatile("s_waitcnt lgkmcnt(0)\n\ts_barrier" ::: "memory");
}

// ---- per-LSTM scale: max(|Whh|, |Wih|, |bih+bhh|/2), via atomicMax on float bits.
__global__ void scale_k(const float* Ws_ih, const float* Ws_hh, const float* bs_ih, const float* bs_hh,
                        const float* Wp_ih, const float* Wp_hh, const float* bp_ih, const float* bp_hh,
                        const float* Wd_ih, const float* Wd_hh, const float* bd_ih, const float* bd_hh,
                        int* smax)
{
    int L = blockIdx.x >> 5;
    int blk = blockIdx.x & 31;
    const float* Wih = L==0 ? Ws_ih : L==1 ? Wp_ih : Wd_ih;
    const float* Whh = L==0 ? Ws_hh : L==1 ? Wp_hh : Wd_hh;
    const float* bih = L==0 ? bs_ih : L==1 ? bp_ih : bd_ih;
    const float* bhh = L==0 ? bs_hh : L==1 ? bp_hh : bd_hh;
    float m = 0.f;
    for (int i = blk*256 + threadIdx.x; i < 2048*512; i += 32*256) m = fmaxf(m, fabsf(Whh[i]));
    for (int i = blk*256 + threadIdx.x; i < 2048*4;   i += 32*256) m = fmaxf(m, fabsf(Wih[i]));
    for (int i = blk*256 + threadIdx.x; i < 2048;     i += 32*256) m = fmaxf(m, 0.5f*fabsf(bih[i]+bhh[i]));
    __shared__ float red[256];
    red[threadIdx.x] = m; __syncthreads();
    for (int s = 128; s; s >>= 1){
        if (threadIdx.x < s) red[threadIdx.x] = fmaxf(red[threadIdx.x], red[threadIdx.x+s]);
        __syncthreads();
    }
    if (threadIdx.x == 0) atomicMax(&smax[L], __float_as_int(red[0]));
}

// Pack: BP[chunk(16)][kt(9)][nt(8)][lane(64)][16 i8]; element B[k][n]:
// n=(chunk*8+nt)*16+(lane&15), k=kt*64+(lane>>4)*16+j. Packed n decode: ch=n>>7,
// g=(n>>5)&3, u=n&31 -> row=g*512+ch*32+u. K rows: 0..511=Whh; 512..527=Wih
// x-replicas; 528..529=(b_ih+b_hh)/2; 530..575=0. NOTE: tile kt=8 (k>=512) is
// still packed but NO LONGER READ by lstm_all — its contribution is applied
// exactly in the epilogue via the side tables from tab_k.
__global__ void pack_k(const float* Wih, const float* Whh, const float* bih, const float* bhh,
                       const int* smax, int L, unsigned char* dst, float* gsout)
{
    int f4 = blockIdx.x*256 + threadIdx.x;
    if (f4*4 >= LSTR) return;
    float mx = __int_as_float(smax[L]);
    float inv = 127.f / mx;
    if (blockIdx.x==0 && threadIdx.x==0) gsout[L] = mx * (1.f/(127.f*127.f));
    int fb = f4*4;
    int lane=(fb>>4)&63, nt=(fb>>10)&7, t=fb>>13;
    int kt=t%9, chunk=t/9;
    int n = (chunk*8+nt)*16 + (lane&15);
    int ch=n>>7, g=(n>>5)&3, u=n&31;
    int row = g*512 + ch*32 + u;
    int kbase = kt*64 + ((lane>>4)<<4) + (fb&15);
    unsigned out = 0;
    #pragma unroll
    for (int b=0;b<4;++b){
        int k = kbase + b;
        float v = 0.f;
        if (k < 512)      v = Whh[row*512+k];
        else if (k < 528) v = Wih[row*4 + (k&3)];
        else if (k < 530) v = 0.5f*(bih[row]+bhh[row]);
        int q = (int)rintf(v*inv);
        q = q>127?127:(q<-127?-127:q);
        out |= ((unsigned)(q & 255)) << (8*b);
    }
    *(unsigned*)(dst + fb) = out;
}

// Side tables for the epilogue x/bias correction, indexed by PACKED n.
// swt[n] = 4x int8 quantized Wih row (same rint/clamp as pack_k);
// sbt[n] = 254 * quantized((bih+bhh)/2)  [= 2 cols x A=127 x bq, exactly
// what the dropped tile-8 MFMA contributed].
__global__ void tab_k(const float* Wih, const float* bih, const float* bhh,
                      const int* smax, int L, int* swt, int* sbt)
{
    int n = blockIdx.x*256 + threadIdx.x;
    if (n >= 2048) return;
    float inv = 127.f / __int_as_float(smax[L]);
    int ch=n>>7, g=(n>>5)&3, u=n&31;
    int row = g*512 + ch*32 + u;
    unsigned w = 0;
    #pragma unroll
    for (int d=0; d<4; ++d){
        int q = (int)rintf(Wih[row*4+d]*inv);
        q = q>127?127:(q<-127?-127:q);
        w |= ((unsigned)(q & 255)) << (8*d);
    }
    swt[n] = (int)w;
    int qb = (int)rintf(0.5f*(bih[row]+bhh[row])*inv);
    qb = qb>127?127:(qb<-127?-127:qb);
    sbt[n] = 254*qb;
}

__global__ __launch_bounds__(NTHR, 1)
void lstm_all(const float* __restrict__ speed, const float* __restrict__ pos,
              const unsigned char* __restrict__ wpack, const float* __restrict__ gsb,
              const int* __restrict__ swt, const int* __restrict__ sbt,
              const float* __restrict__ wfc, const float* __restrict__ bfc,
              const float* __restrict__ wemb, const float* __restrict__ bemb,
              float* __restrict__ out)
{
    __shared__ __align__(16) unsigned char abuf[2][MTILE][KPADI];  // 37888 B
    __shared__ __align__(16) unsigned char hsave[MTILE][HSTR];     // 16896 B
    __shared__ float csave[MTILE][512];                            // 65536 B
    __shared__ int swl[2048];                                      // 8192 B (stage Wih table)
    __shared__ int sbl[2048];                                      // 8192 B (stage bias table)
    __shared__ float smallw[1040];
    __shared__ float partial[NTHR];

    const int tid  = threadIdx.x;
    const int lane = tid & 63;
    const int wv   = tid >> 6;          // 0..7
    const int row0 = blockIdx.x * MTILE;
    const int l15  = lane & 15;
    const int lq   = lane >> 4;
    const int cstag = blockIdx.x & 15;  // chunk stagger across blocks
    const int ch0 = (2*wv + 0 + cstag) & 15;
    const int ch1 = (2*wv + 1 + cstag) & 15;

    const float gs0 = gsb[0], gs1 = gsb[1], gs2 = gsb[2];

    const unsigned char* wsp = wpack;
    const unsigned char* wpp = wpack + (size_t)LSTR;
    const unsigned char* wdp = wpack + 2*(size_t)LSTR;

    // ---- init LDS ----
    {
        for (int i = tid; i < 2*MTILE*(KPADI/16); i += NTHR) {
            int b = i / (MTILE*(KPADI/16));
            int rmd = i % (MTILE*(KPADI/16));
            int m = rmd / (KPADI/16), c16 = (rmd % (KPADI/16))*16;
            *(int4v*)&abuf[b][m][c16] = (int4v){0,0,0,0};
        }
        for (int i = tid; i < 2048; i += NTHR){ swl[i] = swt[i]; sbl[i] = sbt[i]; }
        for (int i = tid; i < 1024; i += NTHR) smallw[i] = wfc[i];
        if (tid < 2) smallw[1024+tid] = bfc[tid];
        if (tid < 8) smallw[1026+tid] = wemb[tid];
        if (tid < 4) smallw[1034+tid] = bemb[tid];
    }
    lbar();
    if (tid < 128) {
        int m = tid>>2, f3 = tid&3;
        float x = speed[((size_t)(row0+m)*16 + 0)*4 + f3];
        int q = (int)rintf(fminf(fmaxf(x*31.75f,-127.f),127.f));
        unsigned char qb = (unsigned char)q;
        abuf[0][m][512+f3]=qb; abuf[0][m][516+f3]=qb; abuf[0][m][520+f3]=qb; abuf[0][m][524+f3]=qb;
    }
    lbar();

    float cc0[16], cc1[16];
    #pragma unroll
    for (int i = 0; i < 16; ++i) { cc0[i]=0.f; cc1[i]=0.f; }

    int4v bA[8], bB[8];   // persistent ping-pong weight-tile buffers (cross-step warm start)

    // Epilogue: integer x/bias correction (exactly the dropped tile-8 MFMA),
    // then gate nonlinearities. xq is read from LDS HERE (not held in registers
    // across the k-loops — r6's xr[8] live range was spilled into the hot loop:
    // 219 MB scratch writes). abuf[rb] x-slots (cols 512+) are stable during
    // the step: h-writes touch cols 0..511, next-step staging writes abuf[wbuf].
    auto epi = [&](int4v (&acc)[2][8], float (&cc)[16], int chunk, int rb, int wbuf,
                   float nK1, float nK2){
        const int nb = chunk*128 + l15;
        #pragma unroll
        for (int up=0;up<2;++up){
            int w0 = swl[nb+(0+up)*16], w1 = swl[nb+(2+up)*16];
            int w2 = swl[nb+(4+up)*16], w3 = swl[nb+(6+up)*16];
            int b0 = sbl[nb+(0+up)*16], b1 = sbl[nb+(2+up)*16];
            int b2 = sbl[nb+(4+up)*16], b3 = sbl[nb+(6+up)*16];
            #pragma unroll
            for (int mf=0;mf<2;++mf)
                #pragma unroll
                for (int r=0;r<4;++r){
                    int idx = (mf*2+up)*4 + r;
                    int xq = *(const int*)&abuf[rb][mf*16+lq*4+r][512];
                    float fi = (float)(acc[mf][0+up][r] + 4*dot4i8(xq,w0) + b0);
                    float ff = (float)(acc[mf][2+up][r] + 4*dot4i8(xq,w1) + b1);
                    float fg = (float)(acc[mf][4+up][r] + 4*dot4i8(xq,w2) + b2);
                    float fo = (float)(acc[mf][6+up][r] + 4*dot4i8(xq,w3) + b3);
                    float si = rcpf_(1.f+ex2(nK1*fi));     // sig(gs*acc), gs folded
                    float sf = rcpf_(1.f+ex2(nK1*ff));
                    float so = rcpf_(1.f+ex2(nK1*fo));
                    float tg = 2.f*rcpf_(1.f+ex2(nK2*fg)) - 1.f;  // tanh(gs*acc)
                    float cn = sf*cc[idx] + si*tg;
                    cc[idx] = cn;
                    float h = so*tanh_(cn);
                    int q = (int)rintf(h*127.f);
                    abuf[wbuf][mf*16+lq*4+r][chunk*32+up*16+l15] = (unsigned char)q;
                }
        }
    };

    // Fused step: both chunk-passes over k-tiles 0..7 ONLY (tile 8 replaced by
    // the exact epilogue correction -> 16 instead of 18 tiles/step streamed,
    // 256 instead of 288 MFMAs). Even tile count = clean ping-pong; bA enters
    // each chunk holding t0 (warm across steps via PF), bB is the transient.
    auto step2 = [&](int rb, int wbuf, const unsigned char* wl,
                     float (&c0)[16], float (&c1)[16], float gs, int WARM, int PF){
        const unsigned char* bp0 = wl + (size_t)ch0*CHB + lane*16;
        const unsigned char* bp1 = wl + (size_t)ch1*CHB + lane*16;
        const unsigned char* ar0 = &abuf[rb][l15][0];
        const unsigned char* ar1 = &abuf[rb][16+l15][0];
        const float nK1 = -gs*LOG2E, nK2 = -2.f*gs*LOG2E;
        int4v acc[2][8];
        if (!WARM){
            #pragma unroll
            for (int nt=0;nt<8;++nt) bA[nt] = *(const int4v*)(bp0 + nt*1024);
        }
        // ---- chunk 0 ----
        #pragma unroll
        for (int mf=0;mf<2;++mf)
            #pragma unroll
            for (int nt=0;nt<8;++nt) acc[mf][nt] = (int4v){0,0,0,0};
        #pragma unroll 1
        for (int kt=0; kt<6; kt+=2){
            const unsigned char* p1 = bp0 + (kt+1)*8192;
            #pragma unroll
            for (int nt=0;nt<8;++nt) bB[nt] = *(const int4v*)(p1 + nt*1024);
            int4v a0 = *(const int4v*)(ar0 + kt*64 + lq*16);
            int4v a1 = *(const int4v*)(ar1 + kt*64 + lq*16);
            #pragma unroll
            for (int nt=0;nt<8;++nt){
                acc[0][nt] = __builtin_amdgcn_mfma_i32_16x16x64_i8(a0, bA[nt], acc[0][nt], 0,0,0);
                acc[1][nt] = __builtin_amdgcn_mfma_i32_16x16x64_i8(a1, bA[nt], acc[1][nt], 0,0,0);
            }
            const unsigned char* p2 = bp0 + (kt+2)*8192;
            #pragma unroll
            for (int nt=0;nt<8;++nt) bA[nt] = *(const int4v*)(p2 + nt*1024);
            a0 = *(const int4v*)(ar0 + (kt+1)*64 + lq*16);
            a1 = *(const int4v*)(ar1 + (kt+1)*64 + lq*16);
            #pragma unroll
            for (int nt=0;nt<8;++nt){
                acc[0][nt] = __builtin_amdgcn_mfma_i32_16x16x64_i8(a0, bB[nt], acc[0][nt], 0,0,0);
                acc[1][nt] = __builtin_amdgcn_mfma_i32_16x16x64_i8(a1, bB[nt], acc[1][nt], 0,0,0);
            }
        }
        {   // peel kt=6,7: consume t6 (bA), t7 (bB); seam-load chunk1 t0 -> bA
            const unsigned char* p1 = bp0 + 7*8192;
            #pragma unroll
            for (int nt=0;nt<8;++nt) bB[nt] = *(const int4v*)(p1 + nt*1024);
            int4v a0 = *(const int4v*)(ar0 + 6*64 + lq*16);
            int4v a1 = *(const int4v*)(ar1 + 6*64 + lq*16);
            #pragma unroll
            for (int nt=0;nt<8;++nt){
                acc[0][nt] = __builtin_amdgcn_mfma_i32_16x16x64_i8(a0, bA[nt], acc[0][nt], 0,0,0);
                acc[1][nt] = __builtin_amdgcn_mfma_i32_16x16x64_i8(a1, bA[nt], acc[1][nt], 0,0,0);
            }
            #pragma unroll
            for (int nt=0;nt<8;++nt) bA[nt] = *(const int4v*)(bp1 + nt*1024);
            a0 = *(const int4v*)(ar0 + 7*64 + lq*16);
            a1 = *(const int4v*)(ar1 + 7*64 + lq*16);
            #pragma unroll
            for (int nt=0;nt<8;++nt){
                acc[0][nt] = __builtin_amdgcn_mfma_i32_16x16x64_i8(a0, bB[nt], acc[0][nt], 0,0,0);
                acc[1][nt] = __builtin_amdgcn_mfma_i32_16x16x64_i8(a1, bB[nt], acc[1][nt], 0,0,0);
            }
        }
        epi(acc, c0, ch0, rb, wbuf, nK1, nK2);
        // ---- chunk 1 (bA = t0, in flight since the seam) ----
        #pragma unroll
        for (int mf=0;mf<2;++mf)
            #pragma unroll
            for (int nt=0;nt<8;++nt) acc[mf][nt] = (int4v){0,0,0,0};
        #pragma unroll 1
        for (int kt=0; kt<6; kt+=2){
            const unsigned char* p1 = bp1 + (kt+1)*8192;
            #pragma unroll
            for (int nt=0;nt<8;++nt) bB[nt] = *(const int4v*)(p1 + nt*1024);
            int4v a0 = *(const int4v*)(ar0 + kt*64 + lq*16);
            int4v a1 = *(const int4v*)(ar1 + kt*64 + lq*16);
            #pragma unroll
            for (int nt=0;nt<8;++nt){
                acc[0][nt] = __builtin_amdgcn_mfma_i32_16x16x64_i8(a0, bA[nt], acc[0][nt], 0,0,0);
                acc[1][nt] = __builtin_amdgcn_mfma_i32_16x16x64_i8(a1, bA[nt], acc[1][nt], 0,0,0);
            }
            const unsigned char* p2 = bp1 + (kt+2)*8192;
            #pragma unroll
            for (int nt=0;nt<8;++nt) bA[nt] = *(const int4v*)(p2 + nt*1024);
            a0 = *(const int4v*)(ar0 + (kt+1)*64 + lq*16);
            a1 = *(const int4v*)(ar1 + (kt+1)*64 + lq*16);
            #pragma unroll
            for (int nt=0;nt<8;++nt){
                acc[0][nt] = __builtin_amdgcn_mfma_i32_16x16x64_i8(a0, bB[nt], acc[0][nt], 0,0,0);
                acc[1][nt] = __builtin_amdgcn_mfma_i32_16x16x64_i8(a1, bB[nt], acc[1][nt], 0,0,0);
            }
        }
        {   // peel kt=6,7; cross-step prefetch of next chunk0 t0 -> bA
            const unsigned char* p1 = bp1 + 7*8192;
            #pragma unroll
            for (int nt=0;nt<8;++nt) bB[nt] = *(const int4v*)(p1 + nt*1024);
            int4v a0 = *(const int4v*)(ar0 + 6*64 + lq*16);
            int4v a1 = *(const int4v*)(ar1 + 6*64 + lq*16);
            #pragma unroll
            for (int nt=0;nt<8;++nt){
                acc[0][nt] = __builtin_amdgcn_mfma_i32_16x16x64_i8(a0, bA[nt], acc[0][nt], 0,0,0);
                acc[1][nt] = __builtin_amdgcn_mfma_i32_16x16x64_i8(a1, bA[nt], acc[1][nt], 0,0,0);
            }
            if (PF){
                #pragma unroll
                for (int nt=0;nt<8;++nt) bA[nt] = *(const int4v*)(bp0 + nt*1024);
            }
            a0 = *(const int4v*)(ar0 + 7*64 + lq*16);
            a1 = *(const int4v*)(ar1 + 7*64 + lq*16);
            #pragma unroll
            for (int nt=0;nt<8;++nt){
                acc[0][nt] = __builtin_amdgcn_mfma_i32_16x16x64_i8(a0, bB[nt], acc[0][nt], 0,0,0);
                acc[1][nt] = __builtin_amdgcn_mfma_i32_16x16x64_i8(a1, bB[nt], acc[1][nt], 0,0,0);
            }
        }
        epi(acc, c1, ch1, rb, wbuf, nK1, nK2);
    };

    // Dual-source pass (decoder t=0 only): gates = Wd*h_p + Wd*h_s (+ x/bias
    // correction in the epilogue), defer h. Two uniform 8-tile passes.
    auto pass_dual = [&](const unsigned char* wl, int s, float (&cc)[16], float gs, int (&hq)[16]) {
        const int chunk = s ? ch1 : ch0;
        const unsigned char* bp = wl + (size_t)chunk*CHB + lane*16;
        const unsigned char* ar0 = &abuf[0][l15][0];
        const unsigned char* ar1 = &abuf[0][16+l15][0];
        int4v acc[2][8];
        #pragma unroll
        for (int mf=0;mf<2;++mf)
            #pragma unroll
            for (int nt=0;nt<8;++nt) acc[mf][nt] = (int4v){0,0,0,0};
        #pragma unroll
        for (int nt=0;nt<8;++nt) bA[nt] = *(const int4v*)(bp + nt*1024);
        // pass 1: h_p (abuf[0]), tiles 0..7
        #pragma unroll 1
        for (int kt=0; kt<6; kt+=2){
            const unsigned char* p1 = bp + (kt+1)*8192;
            #pragma unroll
            for (int nt=0;nt<8;++nt) bB[nt] = *(const int4v*)(p1 + nt*1024);
            int4v a0 = *(const int4v*)(ar0 + kt*64 + lq*16);
            int4v a1 = *(const int4v*)(ar1 + kt*64 + lq*16);
            #pragma unroll
            for (int nt=0;nt<8;++nt){
                acc[0][nt] = __builtin_amdgcn_mfma_i32_16x16x64_i8(a0, bA[nt], acc[0][nt], 0,0,0);
                acc[1][nt] = __builtin_amdgcn_mfma_i32_16x16x64_i8(a1, bA[nt], acc[1][nt], 0,0,0);
            }
            const unsigned char* p2 = bp + (kt+2)*8192;
            #pragma unroll
            for (int nt=0;nt<8;++nt) bA[nt] = *(const int4v*)(p2 + nt*1024);
            a0 = *(const int4v*)(ar0 + (kt+1)*64 + lq*16);
            a1 = *(const int4v*)(ar1 + (kt+1)*64 + lq*16);
            #pragma unroll
            for (int nt=0;nt<8;++nt){
                acc[0][nt] = __builtin_amdgcn_mfma_i32_16x16x64_i8(a0, bB[nt], acc[0][nt], 0,0,0);
                acc[1][nt] = __builtin_amdgcn_mfma_i32_16x16x64_i8(a1, bB[nt], acc[1][nt], 0,0,0);
            }
        }
        {   // peel kt=6,7; reload t0 -> bA for pass 2
            const unsigned char* p1 = bp + 7*8192;
            #pragma unroll
            for (int nt=0;nt<8;++nt) bB[nt] = *(const int4v*)(p1 + nt*1024);
            int4v a0 = *(const int4v*)(ar0 + 6*64 + lq*16);
            int4v a1 = *(const int4v*)(ar1 + 6*64 + lq*16);
            #pragma unroll
            for (int nt=0;nt<8;++nt){
                acc[0][nt] = __builtin_amdgcn_mfma_i32_16x16x64_i8(a0, bA[nt], acc[0][nt], 0,0,0);
                acc[1][nt] = __builtin_amdgcn_mfma_i32_16x16x64_i8(a1, bA[nt], acc[1][nt], 0,0,0);
            }
            #pragma unroll
            for (int nt=0;nt<8;++nt) bA[nt] = *(const int4v*)(bp + nt*1024);
            a0 = *(const int4v*)(ar0 + 7*64 + lq*16);
            a1 = *(const int4v*)(ar1 + 7*64 + lq*16);
            #pragma unroll
            for (int nt=0;nt<8;++nt){
                acc[0][nt] = __builtin_amdgcn_mfma_i32_16x16x64_i8(a0, bB[nt], acc[0][nt], 0,0,0);
                acc[1][nt] = __builtin_amdgcn_mfma_i32_16x16x64_i8(a1, bB[nt], acc[1][nt], 0,0,0);
            }
        }
        // pass 2: h_s (hsave), tiles 0..7
        {
            const unsigned char* hr0 = &hsave[l15][0];
            const unsigned char* hr1 = &hsave[16+l15][0];
            #pragma unroll 1
            for (int kt=0; kt<6; kt+=2){
                const unsigned char* p1 = bp + (kt+1)*8192;
                #pragma unroll
                for (int nt=0;nt<8;++nt) bB[nt] = *(const int4v*)(p1 + nt*1024);
                int4v a0 = *(const int4v*)(hr0 + kt*64 + lq*16);
                int4v a1 = *(const int4v*)(hr1 + kt*64 + lq*16);
                #pragma unroll
                for (int nt=0;nt<8;++nt){
                    acc[0][nt] = __builtin_amdgcn_mfma_i32_16x16x64_i8(a0, bA[nt], acc[0][nt], 0,0,0);
                    acc[1][nt] = __builtin_amdgcn_mfma_i32_16x16x64_i8(a1, bA[nt], acc[1][nt], 0,0,0);
                }
                const unsigned char* p2 = bp + (kt+2)*8192;
                #pragma unroll
                for (int nt=0;nt<8;++nt) bA[nt] = *(const int4v*)(p2 + nt*1024);
                a0 = *(const int4v*)(hr0 + (kt+1)*64 + lq*16);
                a1 = *(const int4v*)(hr1 + (kt+1)*64 + lq*16);
                #pragma unroll
                for (int nt=0;nt<8;++nt){
                    acc[0][nt] = __builtin_amdgcn_mfma_i32_16x16x64_i8(a0, bB[nt], acc[0][nt], 0,0,0);
                    acc[1][nt] = __builtin_amdgcn_mfma_i32_16x16x64_i8(a1, bB[nt], acc[1][nt], 0,0,0);
                }
            }
            {   // peel kt=6,7
                const unsigned char* p1 = bp + 7*8192;
                #pragma unroll
                for (int nt=0;nt<8;++nt) bB[nt] = *(const int4v*)(p1 + nt*1024);
                int4v a0 = *(const int4v*)(hr0 + 6*64 + lq*16);
                int4v a1 = *(const int4v*)(hr1 + 6*64 + lq*16);
                #pragma unroll
                for (int nt=0;nt<8;++nt){
                    acc[0][nt] = __builtin_amdgcn_mfma_i32_16x16x64_i8(a0, bA[nt], acc[0][nt], 0,0,0);
                    acc[1][nt] = __builtin_amdgcn_mfma_i32_16x16x64_i8(a1, bA[nt], acc[1][nt], 0,0,0);
                }
                a0 = *(const int4v*)(hr0 + 7*64 + lq*16);
                a1 = *(const int4v*)(hr1 + 7*64 + lq*16);
                #pragma unroll
                for (int nt=0;nt<8;++nt){
                    acc[0][nt] = __builtin_amdgcn_mfma_i32_16x16x64_i8(a0, bB[nt], acc[0][nt], 0,0,0);
                    acc[1][nt] = __builtin_amdgcn_mfma_i32_16x16x64_i8(a1, bB[nt], acc[1][nt], 0,0,0);
                }
            }
        }
        {   // epilogue with x/bias correction (xq read from LDS, not registers)
            const int nb = chunk*128 + l15;
            #pragma unroll
            for (int up=0;up<2;++up){
                int w0 = swl[nb+(0+up)*16], w1 = swl[nb+(2+up)*16];
                int w2 = swl[nb+(4+up)*16], w3 = swl[nb+(6+up)*16];
                int b0 = sbl[nb+(0+up)*16], b1 = sbl[nb+(2+up)*16];
                int b2 = sbl[nb+(4+up)*16], b3 = sbl[nb+(6+up)*16];
                #pragma unroll
                for (int mf=0;mf<2;++mf)
                    #pragma unroll
                    for (int r=0;r<4;++r){
                        int idx = (mf*2+up)*4 + r;
                        int xq = *(const int*)&abuf[0][mf*16+lq*4+r][512];
                        float gi = (float)(acc[mf][0+up][r] + 4*dot4i8(xq,w0) + b0) * gs;
                        float gf = (float)(acc[mf][2+up][r] + 4*dot4i8(xq,w1) + b1) * gs;
                        float gg = (float)(acc[mf][4+up][r] + 4*dot4i8(xq,w2) + b2) * gs;
                        float go = (float)(acc[mf][6+up][r] + 4*dot4i8(xq,w3) + b3) * gs;
                        float cn = sigf(gf)*cc[idx] + sigf(gi)*tanh_(gg);
                        cc[idx] = cn;
                        float h = sigf(go)*tanh_(cn);
                        hq[idx] = (int)rintf(h*127.f);
                    }
            }
        }
    };

    // ---- speed encoder ----
    #pragma unroll 1
    for (int t=0;t<16;++t){
        int rb=t&1, wbuf=(t+1)&1;
        if (t<15 && tid<128){
            int m=tid>>2, f3=tid&3;
            float x = speed[((size_t)(row0+m)*16 + t+1)*4 + f3];
            int q = (int)rintf(fminf(fmaxf(x*31.75f,-127.f),127.f));
            unsigned char qb=(unsigned char)q;
            abuf[wbuf][m][512+f3]=qb; abuf[wbuf][m][516+f3]=qb; abuf[wbuf][m][520+f3]=qb; abuf[wbuf][m][524+f3]=qb;
        }
        step2(rb,wbuf,wsp,cc0,cc1,gs0, (t>0), (t<15));
        lbar();
    }
    // ---- speed -> pos transition (final h_s in abuf[0]) ----
    for (int i=tid; i<MTILE*32; i+=NTHR){
        int m=i>>5, cb=(i&31)*16;
        *(int4v*)&hsave[m][cb] = *(const int4v*)&abuf[0][m][cb];
        *(int4v*)&abuf[0][m][cb] = (int4v){0,0,0,0};
    }
    for (int i = tid; i < 2048; i += NTHR){ swl[i] = swt[2048+i]; sbl[i] = sbt[2048+i]; }
    #pragma unroll
    for (int s2=0;s2<2;++s2)
        #pragma unroll
        for (int mf=0;mf<2;++mf)
            #pragma unroll
            for (int up=0;up<2;++up)
                #pragma unroll
                for (int r=0;r<4;++r){
                    int idx=(mf*2+up)*4+r;
                    int ch=(2*wv+s2+cstag)&15;
                    csave[mf*16+lq*4+r][ch*32+up*16+l15] = s2 ? cc1[idx] : cc0[idx];
                }
    #pragma unroll
    for (int i=0;i<16;++i){ cc0[i]=0.f; cc1[i]=0.f; }
    if (tid < 128) {
        int m = tid>>2, f3 = tid&3;
        float x = pos[((size_t)(row0+m)*16 + 0)*4 + f3];
        int q = (int)rintf(fminf(fmaxf(x*31.75f,-127.f),127.f));
        unsigned char qb = (unsigned char)q;
        abuf[0][m][512+f3]=qb; abuf[0][m][516+f3]=qb; abuf[0][m][520+f3]=qb; abuf[0][m][524+f3]=qb;
    }
    lbar();

    // ---- pos encoder ----
    #pragma unroll 1
    for (int t=0;t<16;++t){
        int rb=t&1, wbuf=(t+1)&1;
        if (t<15 && tid<128){
            int m=tid>>2, f3=tid&3;
            float x = pos[((size_t)(row0+m)*16 + t+1)*4 + f3];
            int q = (int)rintf(fminf(fmaxf(x*31.75f,-127.f),127.f));
            unsigned char qb=(unsigned char)q;
            abuf[wbuf][m][512+f3]=qb; abuf[wbuf][m][516+f3]=qb; abuf[wbuf][m][520+f3]=qb; abuf[wbuf][m][524+f3]=qb;
        }
        step2(rb,wbuf,wpp,cc0,cc1,gs1, (t>0), (t<15));
        lbar();
    }
    // ---- combine: c += c_s; x=pos[:,15,:]; h_p in abuf[0], h_s in hsave ----
    for (int i = tid; i < 2048; i += NTHR){ swl[i] = swt[4096+i]; sbl[i] = sbt[4096+i]; }
    if (tid < 128) {
        int m = tid>>2, f3 = tid&3;
        float x = pos[((size_t)(row0+m)*16 + 15)*4 + f3];
        int q = (int)rintf(fminf(fmaxf(x*31.75f,-127.f),127.f));
        unsigned char qb = (unsigned char)q;
        abuf[0][m][512+f3]=qb; abuf[0][m][516+f3]=qb; abuf[0][m][520+f3]=qb; abuf[0][m][524+f3]=qb;
    }
    #pragma unroll
    for (int s2=0;s2<2;++s2)
        #pragma unroll
        for (int mf=0;mf<2;++mf)
            #pragma unroll
            for (int up=0;up<2;++up)
                #pragma unroll
                for (int r=0;r<4;++r){
                    int idx=(mf*2+up)*4+r;
                    int ch=(2*wv+s2+cstag)&15;
                    float v = csave[mf*16+lq*4+r][ch*32+up*16+l15];
                    if (s2) cc1[idx]+=v; else cc0[idx]+=v;
                }
    lbar();

    // ---- decoder ----
    #pragma unroll 1
    for (int t=0;t<16;++t){
        int hb;
        if (t == 0) {
            int hq0[16], hq1[16];
            pass_dual(wdp, 0, cc0, gs2, hq0);
            pass_dual(wdp, 1, cc1, gs2, hq1);
            lbar();
            #pragma unroll
            for (int s2=0;s2<2;++s2)
                #pragma unroll
                for (int mf=0;mf<2;++mf)
                    #pragma unroll
                    for (int up=0;up<2;++up)
                        #pragma unroll
                        for (int r=0;r<4;++r){
                            int idx=(mf*2+up)*4+r;
                            int ch=(2*wv+s2+cstag)&15;
                            int q = s2 ? hq1[idx] : hq0[idx];
                            abuf[0][mf*16+lq*4+r][ch*32+up*16+l15] = (unsigned char)q;
                        }
            hb = 0;
        } else {
            int rb=(t+1)&1, wbuf=t&1;
            step2(rb,wbuf,wdp,cc0,cc1,gs2, (t>1), (t<15));
            hb = wbuf;
        }
        lbar();
        {   // crossing partials: wave wv covers k-slice [wv*64, wv*64+64)
            int r = lane>>1, col = lane&1;
            const unsigned char* hp = &abuf[hb][r][wv*64];
            const float* wp = &smallw[col*512 + wv*64];
            float p = 0.f;
            #pragma unroll
            for (int k4=0;k4<16;++k4){
                int v = *(const int*)(hp + k4*4);
                p += (float)((signed char)(v    )) * wp[k4*4+0];
                p += (float)((signed char)(v>>8 )) * wp[k4*4+1];
                p += (float)((signed char)(v>>16)) * wp[k4*4+2];
                p += (float)((signed char)(v>>24)) * wp[k4*4+3];
            }
            partial[wv*64 + lane] = p;
        }
        lbar();
        if (wv == 0) {
            float p = 0.f;
            #pragma unroll
            for (int i=0;i<8;++i) p += partial[i*64 + lane];
            int r = lane>>1, col = lane&1;
            p = p*(1.f/127.f) + smallw[1024+col];
            float cr = fmaxf(p, 0.f);
            float other = __shfl_xor(cr, 1, 64);
            float mx = fmaxf(cr, other);
            float e0 = ex2(LOG2E*(cr-mx)), e1 = ex2(LOG2E*(other-mx));
            out[((size_t)(row0+r))*32 + t*2 + col] = e0*rcpn(e0+e1);
            float c0v = col ? other : cr;
            float c1v = col ? cr : other;
            #pragma unroll
            for (int q2=0;q2<2;++q2){
                int e = col*2 + q2;
                float lp = fmaxf(c0v*smallw[1026+e*2] + c1v*smallw[1026+e*2+1] + smallw[1034+e], 0.f);
                int qv = (int)rintf(fminf(lp*31.75f, 127.f));
                unsigned char qb = (unsigned char)qv;
                abuf[hb][r][512+e]=qb; abuf[hb][r][516+e]=qb; abuf[hb][r][520+e]=qb; abuf[hb][r][524+e]=qb;
            }
        }
        lbar();
    }
}

extern "C" void kernel_launch(void* const* d_in, const int* in_sizes, int n_in,
                              void* d_out, int out_size, void* d_ws, size_t ws_size,
                              hipStream_t stream)
{
    (void)in_sizes; (void)n_in; (void)out_size; (void)ws_size;
    const float* speed = (const float*)d_in[0];
    const float* pos   = (const float*)d_in[1];
    const float* Ws_ih = (const float*)d_in[2];
    const float* Ws_hh = (const float*)d_in[3];
    const float* bs_ih = (const float*)d_in[4];
    const float* bs_hh = (const float*)d_in[5];
    const float* Wp_ih = (const float*)d_in[6];
    const float* Wp_hh = (const float*)d_in[7];
    const float* bp_ih = (const float*)d_in[8];
    const float* bp_hh = (const float*)d_in[9];
    const float* Wd_ih = (const float*)d_in[10];
    const float* Wd_hh = (const float*)d_in[11];
    const float* bd_ih = (const float*)d_in[12];
    const float* bd_hh = (const float*)d_in[13];
    const float* W_fc  = (const float*)d_in[14];
    const float* b_fc  = (const float*)d_in[15];
    const float* W_emb = (const float*)d_in[16];
    const float* b_emb = (const float*)d_in[17];

    unsigned char* wp8 = (unsigned char*)d_ws;
    int*   smax  = (int*)(wp8 + 3*(size_t)LSTR);
    float* gsout = (float*)(wp8 + 3*(size_t)LSTR + 16);
    int*   swt   = (int*)(wp8 + 3*(size_t)LSTR + 64);
    int*   sbt   = swt + 3*2048;

    scale_k<<<96, 256, 0, stream>>>(Ws_ih,Ws_hh,bs_ih,bs_hh, Wp_ih,Wp_hh,bp_ih,bp_hh,
                                    Wd_ih,Wd_hh,bd_ih,bd_hh, smax);
    int gb = (LSTR/4 + 255) / 256;
    pack_k<<<gb, 256, 0, stream>>>(Ws_ih, Ws_hh, bs_ih, bs_hh, smax, 0, wp8,                  gsout);
    pack_k<<<gb, 256, 0, stream>>>(Wp_ih, Wp_hh, bp_ih, bp_hh, smax, 1, wp8 +   (size_t)LSTR, gsout);
    pack_k<<<gb, 256, 0, stream>>>(Wd_ih, Wd_hh, bd_ih, bd_hh, smax, 2, wp8 + 2*(size_t)LSTR, gsout);
    tab_k<<<8, 256, 0, stream>>>(Ws_ih, bs_ih, bs_hh, smax, 0, swt,        sbt);
    tab_k<<<8, 256, 0, stream>>>(Wp_ih, bp_ih, bp_hh, smax, 1, swt + 2048, sbt + 2048);
    tab_k<<<8, 256, 0, stream>>>(Wd_ih, bd_ih, bd_hh, smax, 2, swt + 4096, sbt + 4096);
    lstm_all<<<NBLK, NTHR, 0, stream>>>(speed, pos, wp8, gsout, swt, sbt,
                                        W_fc, b_fc, W_emb, b_emb, (float*)d_out);
}

// Round 8
// 1130.666 us; speedup vs baseline: 1.0511x; 1.0511x over previous
//
#include <hip/hip_runtime.h>

#define NBLK 256
#define NTHR 512
#define MTILE 32
#define KPADI 592                // abuf row stride bytes (16-aligned)
#define HSTR  528                // hsave row stride bytes
#define CHB   (9*8*64*16)        // 73728 bytes per 16-col chunk per LSTM (9 k-tiles of K=64)
#define LSTR  (16*CHB)           // 1179648 bytes per LSTM

typedef __attribute__((ext_vector_type(4))) int int4v;

__device__ inline float ex2(float x){ return __builtin_amdgcn_exp2f(x); }
__device__ inline float rcpf_(float d){ return __builtin_amdgcn_rcpf(d); }
__device__ inline float rcpn(float d){ float r=__builtin_amdgcn_rcpf(d); return r*(2.f-d*r); }
#define LOG2E 1.4426950408889634f
__device__ inline float sigf(float x){ return rcpf_(1.f+ex2(-LOG2E*x)); }
__device__ inline float tanh_(float x){ return 2.f*rcpf_(1.f+ex2(-2.f*LOG2E*x))-1.f; }

// Barrier draining only LDS ops (lgkmcnt); global loads stay in flight.
// Measured neutral vs __syncthreads (r0 719 vs r4 728) — kept so the 2-deep
// weight prefetch survives every step barrier.
__device__ inline void lbar(){
    asm volatile("s_waitcnt lgkmcnt(0)\n\ts_barrier" ::: "memory");
}

// Deep-shifted 9-tile chunk pass. ENTERS with BX=t0, BY=t1 already issued.
// Loads run 16-MFMAs-ahead of consumption (~340 cyc/wave vs r4's ~170 —
// covering L2 latency). EXITS having issued next-chunk t0 -> BY, t1 -> BX
// (2 tiles / 16 KiB in flight across the epilogue + barrier).
// Pure reorder of r4: identical arithmetic, identical peak register liveness
// (no predication, no array params — the proven spill triggers of r1-r3/r5-r7).
#define CHUNK9(BX, BY, AR0, AR1, BP, NXB)                                                   \
    _Pragma("unroll 1")                                                                     \
    for (int kt=0; kt<6; kt+=2){                                                            \
        int4v a0 = *(const int4v*)((AR0) + kt*64 + lq*16);                                  \
        int4v a1 = *(const int4v*)((AR1) + kt*64 + lq*16);                                  \
        _Pragma("unroll")                                                                   \
        for (int nt=0;nt<8;++nt){                                                           \
            acc[0][nt] = __builtin_amdgcn_mfma_i32_16x16x64_i8(a0, BX[nt], acc[0][nt], 0,0,0); \
            acc[1][nt] = __builtin_amdgcn_mfma_i32_16x16x64_i8(a1, BX[nt], acc[1][nt], 0,0,0); \
        }                                                                                   \
        { const unsigned char* p2 = (BP) + (kt+2)*8192;                                     \
          _Pragma("unroll")                                                                 \
          for (int nt=0;nt<8;++nt) BX[nt] = *(const int4v*)(p2 + nt*1024); }                \
        a0 = *(const int4v*)((AR0) + (kt+1)*64 + lq*16);                                    \
        a1 = *(const int4v*)((AR1) + (kt+1)*64 + lq*16);                                    \
        _Pragma("unroll")                                                                   \
        for (int nt=0;nt<8;++nt){                                                           \
            acc[0][nt] = __builtin_amdgcn_mfma_i32_16x16x64_i8(a0, BY[nt], acc[0][nt], 0,0,0); \
            acc[1][nt] = __builtin_amdgcn_mfma_i32_16x16x64_i8(a1, BY[nt], acc[1][nt], 0,0,0); \
        }                                                                                   \
        { const unsigned char* p3 = (BP) + (kt+3)*8192;                                     \
          _Pragma("unroll")                                                                 \
          for (int nt=0;nt<8;++nt) BY[nt] = *(const int4v*)(p3 + nt*1024); }                \
    }                                                                                       \
    {   /* peel kt=6: consume t6(BX); load t8->BX; consume t7(BY); load next t0->BY */      \
        int4v a0 = *(const int4v*)((AR0) + 6*64 + lq*16);                                   \
        int4v a1 = *(const int4v*)((AR1) + 6*64 + lq*16);                                   \
        _Pragma("unroll")                                                                   \
        for (int nt=0;nt<8;++nt){                                                           \
            acc[0][nt] = __builtin_amdgcn_mfma_i32_16x16x64_i8(a0, BX[nt], acc[0][nt], 0,0,0); \
            acc[1][nt] = __builtin_amdgcn_mfma_i32_16x16x64_i8(a1, BX[nt], acc[1][nt], 0,0,0); \
        }                                                                                   \
        { const unsigned char* p8 = (BP) + 8*8192;                                          \
          _Pragma("unroll")                                                                 \
          for (int nt=0;nt<8;++nt) BX[nt] = *(const int4v*)(p8 + nt*1024); }                \
        a0 = *(const int4v*)((AR0) + 7*64 + lq*16);                                         \
        a1 = *(const int4v*)((AR1) + 7*64 + lq*16);                                         \
        _Pragma("unroll")                                                                   \
        for (int nt=0;nt<8;++nt){                                                           \
            acc[0][nt] = __builtin_amdgcn_mfma_i32_16x16x64_i8(a0, BY[nt], acc[0][nt], 0,0,0); \
            acc[1][nt] = __builtin_amdgcn_mfma_i32_16x16x64_i8(a1, BY[nt], acc[1][nt], 0,0,0); \
        }                                                                                   \
        _Pragma("unroll")                                                                   \
        for (int nt=0;nt<8;++nt) BY[nt] = *(const int4v*)((NXB) + nt*1024);                 \
    }                                                                                       \
    {   /* tail: consume t8(BX); load next t1->BX */                                        \
        int4v a0 = *(const int4v*)((AR0) + 8*64 + lq*16);                                   \
        int4v a1 = *(const int4v*)((AR1) + 8*64 + lq*16);                                   \
        _Pragma("unroll")                                                                   \
        for (int nt=0;nt<8;++nt){                                                           \
            acc[0][nt] = __builtin_amdgcn_mfma_i32_16x16x64_i8(a0, BX[nt], acc[0][nt], 0,0,0); \
            acc[1][nt] = __builtin_amdgcn_mfma_i32_16x16x64_i8(a1, BX[nt], acc[1][nt], 0,0,0); \
        }                                                                                   \
        _Pragma("unroll")                                                                   \
        for (int nt=0;nt<8;++nt) BX[nt] = *(const int4v*)((NXB) + 8192 + nt*1024);          \
    }

// Deep-shifted 8-tile pass (tiles 0..7, no t8 — used for the decoder h_s
// accumulation over hsave, whose x/bias columns are not populated).
// ENTERS BX=t0, BY=t1; EXITS BX=next t0, BY=next t1 (both issued).
#define CHUNK8(BX, BY, AR0, AR1, BP, NXB)                                                   \
    _Pragma("unroll 1")                                                                     \
    for (int kt=0; kt<4; kt+=2){                                                            \
        int4v a0 = *(const int4v*)((AR0) + kt*64 + lq*16);                                  \
        int4v a1 = *(const int4v*)((AR1) + kt*64 + lq*16);                                  \
        _Pragma("unroll")                                                                   \
        for (int nt=0;nt<8;++nt){                                                           \
            acc[0][nt] = __builtin_amdgcn_mfma_i32_16x16x64_i8(a0, BX[nt], acc[0][nt], 0,0,0); \
            acc[1][nt] = __builtin_amdgcn_mfma_i32_16x16x64_i8(a1, BX[nt], acc[1][nt], 0,0,0); \
        }                                                                                   \
        { const unsigned char* p2 = (BP) + (kt+2)*8192;                                     \
          _Pragma("unroll")                                                                 \
          for (int nt=0;nt<8;++nt) BX[nt] = *(const int4v*)(p2 + nt*1024); }                \
        a0 = *(const int4v*)((AR0) + (kt+1)*64 + lq*16);                                    \
        a1 = *(const int4v*)((AR1) + (kt+1)*64 + lq*16);                                    \
        _Pragma("unroll")                                                                   \
        for (int nt=0;nt<8;++nt){                                                           \
            acc[0][nt] = __builtin_amdgcn_mfma_i32_16x16x64_i8(a0, BY[nt], acc[0][nt], 0,0,0); \
            acc[1][nt] = __builtin_amdgcn_mfma_i32_16x16x64_i8(a1, BY[nt], acc[1][nt], 0,0,0); \
        }                                                                                   \
        { const unsigned char* p3 = (BP) + (kt+3)*8192;                                     \
          _Pragma("unroll")                                                                 \
          for (int nt=0;nt<8;++nt) BY[nt] = *(const int4v*)(p3 + nt*1024); }                \
    }                                                                                       \
    {   /* kt=4: consume t4(BX); load t6->BX; consume t5(BY); load t7->BY */                \
        int4v a0 = *(const int4v*)((AR0) + 4*64 + lq*16);                                   \
        int4v a1 = *(const int4v*)((AR1) + 4*64 + lq*16);                                   \
        _Pragma("unroll")                                                                   \
        for (int nt=0;nt<8;++nt){                                                           \
            acc[0][nt] = __builtin_amdgcn_mfma_i32_16x16x64_i8(a0, BX[nt], acc[0][nt], 0,0,0); \
            acc[1][nt] = __builtin_amdgcn_mfma_i32_16x16x64_i8(a1, BX[nt], acc[1][nt], 0,0,0); \
        }                                                                                   \
        { const unsigned char* p2 = (BP) + 6*8192;                                          \
          _Pragma("unroll")                                                                 \
          for (int nt=0;nt<8;++nt) BX[nt] = *(const int4v*)(p2 + nt*1024); }                \
        a0 = *(const int4v*)((AR0) + 5*64 + lq*16);                                         \
        a1 = *(const int4v*)((AR1) + 5*64 + lq*16);                                         \
        _Pragma("unroll")                                                                   \
        for (int nt=0;nt<8;++nt){                                                           \
            acc[0][nt] = __builtin_amdgcn_mfma_i32_16x16x64_i8(a0, BY[nt], acc[0][nt], 0,0,0); \
            acc[1][nt] = __builtin_amdgcn_mfma_i32_16x16x64_i8(a1, BY[nt], acc[1][nt], 0,0,0); \
        }                                                                                   \
        { const unsigned char* p3 = (BP) + 7*8192;                                          \
          _Pragma("unroll")                                                                 \
          for (int nt=0;nt<8;++nt) BY[nt] = *(const int4v*)(p3 + nt*1024); }                \
    }                                                                                       \
    {   /* peel kt=6: consume t6(BX); load next t0->BX; consume t7(BY); load next t1->BY */ \
        int4v a0 = *(const int4v*)((AR0) + 6*64 + lq*16);                                   \
        int4v a1 = *(const int4v*)((AR1) + 6*64 + lq*16);                                   \
        _Pragma("unroll")                                                                   \
        for (int nt=0;nt<8;++nt){                                                           \
            acc[0][nt] = __builtin_amdgcn_mfma_i32_16x16x64_i8(a0, BX[nt], acc[0][nt], 0,0,0); \
            acc[1][nt] = __builtin_amdgcn_mfma_i32_16x16x64_i8(a1, BX[nt], acc[1][nt], 0,0,0); \
        }                                                                                   \
        _Pragma("unroll")                                                                   \
        for (int nt=0;nt<8;++nt) BX[nt] = *(const int4v*)((NXB) + nt*1024);                 \
        a0 = *(const int4v*)((AR0) + 7*64 + lq*16);                                         \
        a1 = *(const int4v*)((AR1) + 7*64 + lq*16);                                         \
        _Pragma("unroll")                                                                   \
        for (int nt=0;nt<8;++nt){                                                           \
            acc[0][nt] = __builtin_amdgcn_mfma_i32_16x16x64_i8(a0, BY[nt], acc[0][nt], 0,0,0); \
            acc[1][nt] = __builtin_amdgcn_mfma_i32_16x16x64_i8(a1, BY[nt], acc[1][nt], 0,0,0); \
        }                                                                                   \
        _Pragma("unroll")                                                                   \
        for (int nt=0;nt<8;++nt) BY[nt] = *(const int4v*)((NXB) + 8192 + nt*1024);          \
    }

// ---- per-LSTM scale: max(|Whh|, |Wih|, |bih+bhh|/2), via atomicMax on float bits.
__global__ void scale_k(const float* Ws_ih, const float* Ws_hh, const float* bs_ih, const float* bs_hh,
                        const float* Wp_ih, const float* Wp_hh, const float* bp_ih, const float* bp_hh,
                        const float* Wd_ih, const float* Wd_hh, const float* bd_ih, const float* bd_hh,
                        int* smax)
{
    int L = blockIdx.x >> 5;
    int blk = blockIdx.x & 31;
    const float* Wih = L==0 ? Ws_ih : L==1 ? Wp_ih : Wd_ih;
    const float* Whh = L==0 ? Ws_hh : L==1 ? Wp_hh : Wd_hh;
    const float* bih = L==0 ? bs_ih : L==1 ? bp_ih : bd_ih;
    const float* bhh = L==0 ? bs_hh : L==1 ? bp_hh : bd_hh;
    float m = 0.f;
    for (int i = blk*256 + threadIdx.x; i < 2048*512; i += 32*256) m = fmaxf(m, fabsf(Whh[i]));
    for (int i = blk*256 + threadIdx.x; i < 2048*4;   i += 32*256) m = fmaxf(m, fabsf(Wih[i]));
    for (int i = blk*256 + threadIdx.x; i < 2048;     i += 32*256) m = fmaxf(m, 0.5f*fabsf(bih[i]+bhh[i]));
    __shared__ float red[256];
    red[threadIdx.x] = m; __syncthreads();
    for (int s = 128; s; s >>= 1){
        if (threadIdx.x < s) red[threadIdx.x] = fmaxf(red[threadIdx.x], red[threadIdx.x+s]);
        __syncthreads();
    }
    if (threadIdx.x == 0) atomicMax(&smax[L], __float_as_int(red[0]));
}

// Pack: BP[chunk(16)][kt(9)][nt(8)][lane(64)][16 i8]; element B[k][n]:
// n=(chunk*8+nt)*16+(lane&15), k=kt*64+(lane>>4)*16+j. Packed n decode: ch=n>>7,
// g=(n>>5)&3, u=n&31 -> row=g*512+ch*32+u. K rows: 0..511=Whh; 512..527=Wih
// x-replicas (A holds x/4, 4 copies per dim); 528..529=(b_ih+b_hh)/2 (A holds 127);
// 530..575=0.
__global__ void pack_k(const float* Wih, const float* Whh, const float* bih, const float* bhh,
                       const int* smax, int L, unsigned char* dst, float* gsout)
{
    int f4 = blockIdx.x*256 + threadIdx.x;
    if (f4*4 >= LSTR) return;
    float mx = __int_as_float(smax[L]);
    float inv = 127.f / mx;
    if (blockIdx.x==0 && threadIdx.x==0) gsout[L] = mx * (1.f/(127.f*127.f));
    int fb = f4*4;
    int lane=(fb>>4)&63, nt=(fb>>10)&7, t=fb>>13;
    int kt=t%9, chunk=t/9;
    int n = (chunk*8+nt)*16 + (lane&15);
    int ch=n>>7, g=(n>>5)&3, u=n&31;
    int row = g*512 + ch*32 + u;
    int kbase = kt*64 + ((lane>>4)<<4) + (fb&15);
    unsigned out = 0;
    #pragma unroll
    for (int b=0;b<4;++b){
        int k = kbase + b;
        float v = 0.f;
        if (k < 512)      v = Whh[row*512+k];
        else if (k < 528) v = Wih[row*4 + (k&3)];
        else if (k < 530) v = 0.5f*(bih[row]+bhh[row]);
        int q = (int)rintf(v*inv);
        q = q>127?127:(q<-127?-127:q);
        out |= ((unsigned)(q & 255)) << (8*b);
    }
    *(unsigned*)(dst + fb) = out;
}

__global__ __launch_bounds__(NTHR, 1)
void lstm_all(const float* __restrict__ speed, const float* __restrict__ pos,
              const unsigned char* __restrict__ wpack, const float* __restrict__ gsb,
              const float* __restrict__ wfc, const float* __restrict__ bfc,
              const float* __restrict__ wemb, const float* __restrict__ bemb,
              float* __restrict__ out)
{
    __shared__ __align__(16) unsigned char abuf[2][MTILE][KPADI];  // 37888 B
    __shared__ __align__(16) unsigned char hsave[MTILE][HSTR];     // 16896 B
    __shared__ float csave[MTILE][512];                            // 65536 B
    __shared__ float smallw[1040];
    __shared__ float partial[NTHR];

    const int tid  = threadIdx.x;
    const int lane = tid & 63;
    const int wv   = tid >> 6;          // 0..7
    const int row0 = blockIdx.x * MTILE;
    const int l15  = lane & 15;
    const int lq   = lane >> 4;
    const int cstag = blockIdx.x & 15;  // chunk stagger across blocks
    const int ch0 = (2*wv + 0 + cstag) & 15;
    const int ch1 = (2*wv + 1 + cstag) & 15;

    const float gs0 = gsb[0], gs1 = gsb[1], gs2 = gsb[2];

    const unsigned char* wsp = wpack;
    const unsigned char* wpp = wpack + (size_t)LSTR;
    const unsigned char* wdp = wpack + 2*(size_t)LSTR;
    const unsigned char* sp0 = wsp + (size_t)ch0*CHB + lane*16;
    const unsigned char* sp1 = wsp + (size_t)ch1*CHB + lane*16;
    const unsigned char* pp0 = wpp + (size_t)ch0*CHB + lane*16;
    const unsigned char* pp1 = wpp + (size_t)ch1*CHB + lane*16;
    const unsigned char* dp0 = wdp + (size_t)ch0*CHB + lane*16;
    const unsigned char* dp1 = wdp + (size_t)ch1*CHB + lane*16;

    int4v bA[8], bB[8];   // persistent ping-pong weight-tile buffers
    // cold start: issue speed chunk0 t0,t1 (latency hides under LDS init;
    // lbar does not drain vmcnt so these stay in flight).
    #pragma unroll
    for (int nt=0;nt<8;++nt) bA[nt] = *(const int4v*)(sp0 + nt*1024);
    #pragma unroll
    for (int nt=0;nt<8;++nt) bB[nt] = *(const int4v*)(sp0 + 8192 + nt*1024);

    // ---- init LDS ----
    {
        for (int i = tid; i < 2*MTILE*(KPADI/16); i += NTHR) {
            int b = i / (MTILE*(KPADI/16));
            int rmd = i % (MTILE*(KPADI/16));
            int m = rmd / (KPADI/16), c16 = (rmd % (KPADI/16))*16;
            *(int4v*)&abuf[b][m][c16] = (int4v){0,0,0,0};
        }
        for (int i = tid; i < 1024; i += NTHR) smallw[i] = wfc[i];
        if (tid < 2) smallw[1024+tid] = bfc[tid];
        if (tid < 8) smallw[1026+tid] = wemb[tid];
        if (tid < 4) smallw[1034+tid] = bemb[tid];
    }
    lbar();
    if (tid < 64) { int b = tid>>5, m = tid&31; abuf[b][m][528] = 127; abuf[b][m][529] = 127; }
    if (tid < 128) {
        int m = tid>>2, f3 = tid&3;
        float x = speed[((size_t)(row0+m)*16 + 0)*4 + f3];
        int q = (int)rintf(fminf(fmaxf(x*31.75f,-127.f),127.f));
        unsigned char qb = (unsigned char)q;
        abuf[0][m][512+f3]=qb; abuf[0][m][516+f3]=qb; abuf[0][m][520+f3]=qb; abuf[0][m][524+f3]=qb;
    }
    lbar();

    float cc0[16], cc1[16];
    #pragma unroll
    for (int i = 0; i < 16; ++i) { cc0[i]=0.f; cc1[i]=0.f; }

    auto epi = [&](int4v (&acc)[2][8], float (&cc)[16], int chunk, int wbuf,
                   float nK1, float nK2){
        #pragma unroll
        for (int mf=0;mf<2;++mf)
            #pragma unroll
            for (int up=0;up<2;++up)
                #pragma unroll
                for (int r=0;r<4;++r){
                    int idx = (mf*2+up)*4 + r;
                    float fi = (float)acc[mf][0+up][r];
                    float ff = (float)acc[mf][2+up][r];
                    float fg = (float)acc[mf][4+up][r];
                    float fo = (float)acc[mf][6+up][r];
                    float si = rcpf_(1.f+ex2(nK1*fi));     // sig(gs*acc), gs folded
                    float sf = rcpf_(1.f+ex2(nK1*ff));
                    float so = rcpf_(1.f+ex2(nK1*fo));
                    float tg = 2.f*rcpf_(1.f+ex2(nK2*fg)) - 1.f;  // tanh(gs*acc)
                    float cn = sf*cc[idx] + si*tg;
                    cc[idx] = cn;
                    float h = so*tanh_(cn);
                    int q = (int)rintf(h*127.f);
                    abuf[wbuf][mf*16+lq*4+r][chunk*32+up*16+l15] = (unsigned char)q;
                }
    };

    // Fused step, 2-deep-entrant: enters bA=c0t0, bB=c0t1 (in flight);
    // exits having issued next-step c0t0 -> bA, c0t1 -> bB.
    auto step2 = [&](int rb, int wbuf, const unsigned char* bp0, const unsigned char* bp1,
                     const unsigned char* np0,
                     float (&c0)[16], float (&c1)[16], float gs){
        const unsigned char* ar0 = &abuf[rb][l15][0];
        const unsigned char* ar1 = &abuf[rb][16+l15][0];
        const float nK1 = -gs*LOG2E, nK2 = -2.f*gs*LOG2E;
        int4v acc[2][8];
        // ---- chunk 0: (bA=t0, bB=t1) -> exits (bB=c1t0, bA=c1t1) ----
        #pragma unroll
        for (int mf=0;mf<2;++mf)
            #pragma unroll
            for (int nt=0;nt<8;++nt) acc[mf][nt] = (int4v){0,0,0,0};
        CHUNK9(bA, bB, ar0, ar1, bp0, bp1)
        epi(acc, c0, ch0, wbuf, nK1, nK2);
        // ---- chunk 1: (bB=t0, bA=t1) -> exits (bA=next t0, bB=next t1) ----
        #pragma unroll
        for (int mf=0;mf<2;++mf)
            #pragma unroll
            for (int nt=0;nt<8;++nt) acc[mf][nt] = (int4v){0,0,0,0};
        CHUNK9(bB, bA, ar0, ar1, bp1, np0)
        epi(acc, c1, ch1, wbuf, nK1, nK2);
    };

    // Dual-source pass (decoder t=0 only): gates = Wd*(h_p,x,b) + Wd*h_s, defer h.
    // s=0: enters (bA=dp0t0,bB=dp0t1), exits (bB=dp1t0,bA=dp1t1).
    // s=1: enters that, exits (bA=dp0t0,bB=dp0t1) for decoder t=1's step2.
    auto pd_epi = [&](int4v (&acc)[2][8], float (&cc)[16], float gs, int (&hq)[16]){
        #pragma unroll
        for (int mf=0;mf<2;++mf)
            #pragma unroll
            for (int up=0;up<2;++up)
                #pragma unroll
                for (int r=0;r<4;++r){
                    int idx = (mf*2+up)*4 + r;
                    float gi = (float)acc[mf][0+up][r] * gs;
                    float gf = (float)acc[mf][2+up][r] * gs;
                    float gg = (float)acc[mf][4+up][r] * gs;
                    float go = (float)acc[mf][6+up][r] * gs;
                    float cn = sigf(gf)*cc[idx] + sigf(gi)*tanh_(gg);
                    cc[idx] = cn;
                    float h = sigf(go)*tanh_(cn);
                    hq[idx] = (int)rintf(h*127.f);
                }
    };

    // ---- speed encoder ----
    #pragma unroll 1
    for (int t=0;t<16;++t){
        int rb=t&1, wbuf=(t+1)&1;
        if (t<15 && tid<128){
            int m=tid>>2, f3=tid&3;
            float x = speed[((size_t)(row0+m)*16 + t+1)*4 + f3];
            int q = (int)rintf(fminf(fmaxf(x*31.75f,-127.f),127.f));
            unsigned char qb=(unsigned char)q;
            abuf[wbuf][m][512+f3]=qb; abuf[wbuf][m][516+f3]=qb; abuf[wbuf][m][520+f3]=qb; abuf[wbuf][m][524+f3]=qb;
        }
        step2(rb,wbuf, sp0, sp1, (t<15)? sp0 : pp0, cc0, cc1, gs0);
        lbar();
    }
    // ---- speed -> pos transition (final h_s in abuf[0]) ----
    for (int i=tid; i<MTILE*32; i+=NTHR){
        int m=i>>5, cb=(i&31)*16;
        *(int4v*)&hsave[m][cb] = *(const int4v*)&abuf[0][m][cb];
        *(int4v*)&abuf[0][m][cb] = (int4v){0,0,0,0};
    }
    #pragma unroll
    for (int s2=0;s2<2;++s2)
        #pragma unroll
        for (int mf=0;mf<2;++mf)
            #pragma unroll
            for (int up=0;up<2;++up)
                #pragma unroll
                for (int r=0;r<4;++r){
                    int idx=(mf*2+up)*4+r;
                    int ch=(2*wv+s2+cstag)&15;
                    csave[mf*16+lq*4+r][ch*32+up*16+l15] = s2 ? cc1[idx] : cc0[idx];
                }
    #pragma unroll
    for (int i=0;i<16;++i){ cc0[i]=0.f; cc1[i]=0.f; }
    if (tid < 128) {
        int m = tid>>2, f3 = tid&3;
        float x = pos[((size_t)(row0+m)*16 + 0)*4 + f3];
        int q = (int)rintf(fminf(fmaxf(x*31.75f,-127.f),127.f));
        unsigned char qb = (unsigned char)q;
        abuf[0][m][512+f3]=qb; abuf[0][m][516+f3]=qb; abuf[0][m][520+f3]=qb; abuf[0][m][524+f3]=qb;
    }
    lbar();

    // ---- pos encoder ----
    #pragma unroll 1
    for (int t=0;t<16;++t){
        int rb=t&1, wbuf=(t+1)&1;
        if (t<15 && tid<128){
            int m=tid>>2, f3=tid&3;
            float x = pos[((size_t)(row0+m)*16 + t+1)*4 + f3];
            int q = (int)rintf(fminf(fmaxf(x*31.75f,-127.f),127.f));
            unsigned char qb=(unsigned char)q;
            abuf[wbuf][m][512+f3]=qb; abuf[wbuf][m][516+f3]=qb; abuf[wbuf][m][520+f3]=qb; abuf[wbuf][m][524+f3]=qb;
        }
        step2(rb,wbuf, pp0, pp1, (t<15)? pp0 : dp0, cc0, cc1, gs1);
        lbar();
    }
    // ---- combine: c += c_s; x=pos[:,15,:]; h_p in abuf[0], h_s in hsave ----
    if (tid < 128) {
        int m = tid>>2, f3 = tid&3;
        float x = pos[((size_t)(row0+m)*16 + 15)*4 + f3];
        int q = (int)rintf(fminf(fmaxf(x*31.75f,-127.f),127.f));
        unsigned char qb = (unsigned char)q;
        abuf[0][m][512+f3]=qb; abuf[0][m][516+f3]=qb; abuf[0][m][520+f3]=qb; abuf[0][m][524+f3]=qb;
    }
    #pragma unroll
    for (int s2=0;s2<2;++s2)
        #pragma unroll
        for (int mf=0;mf<2;++mf)
            #pragma unroll
            for (int up=0;up<2;++up)
                #pragma unroll
                for (int r=0;r<4;++r){
                    int idx=(mf*2+up)*4+r;
                    int ch=(2*wv+s2+cstag)&15;
                    float v = csave[mf*16+lq*4+r][ch*32+up*16+l15];
                    if (s2) cc1[idx]+=v; else cc0[idx]+=v;
                }
    lbar();

    // ---- decoder ----
    #pragma unroll 1
    for (int t=0;t<16;++t){
        int hb;
        if (t == 0) {
            int hq0[16], hq1[16];
            const unsigned char* ar0 = &abuf[0][l15][0];
            const unsigned char* ar1 = &abuf[0][16+l15][0];
            const unsigned char* hr0 = &hsave[l15][0];
            const unsigned char* hr1 = &hsave[16+l15][0];
            int4v acc[2][8];
            // s=0: pass1 h_p+x+b (9 tiles, self-seam), pass2 h_s (8 tiles, seam->dp1)
            #pragma unroll
            for (int mf=0;mf<2;++mf)
                #pragma unroll
                for (int nt=0;nt<8;++nt) acc[mf][nt] = (int4v){0,0,0,0};
            CHUNK9(bA, bB, ar0, ar1, dp0, dp0)      // ends bB=dp0t0, bA=dp0t1
            CHUNK8(bB, bA, hr0, hr1, dp0, dp1)      // ends bB=dp1t0, bA=dp1t1
            pd_epi(acc, cc0, gs2, hq0);
            // s=1: same, chunk dp1; pass2 seam -> dp0 (for decoder t=1)
            #pragma unroll
            for (int mf=0;mf<2;++mf)
                #pragma unroll
                for (int nt=0;nt<8;++nt) acc[mf][nt] = (int4v){0,0,0,0};
            CHUNK9(bB, bA, ar0, ar1, dp1, dp1)      // ends bA=dp1t0, bB=dp1t1
            CHUNK8(bA, bB, hr0, hr1, dp1, dp0)      // ends bA=dp0t0, bB=dp0t1
            pd_epi(acc, cc1, gs2, hq1);
            lbar();
            #pragma unroll
            for (int s2=0;s2<2;++s2)
                #pragma unroll
                for (int mf=0;mf<2;++mf)
                    #pragma unroll
                    for (int up=0;up<2;++up)
                        #pragma unroll
                        for (int r=0;r<4;++r){
                            int idx=(mf*2+up)*4+r;
                            int ch=(2*wv+s2+cstag)&15;
                            int q = s2 ? hq1[idx] : hq0[idx];
                            abuf[0][mf*16+lq*4+r][ch*32+up*16+l15] = (unsigned char)q;
                        }
            hb = 0;
        } else {
            int rb=(t+1)&1, wbuf=t&1;
            step2(rb,wbuf, dp0, dp1, dp0, cc0, cc1, gs2);  // t=15 seam loads harmless
            hb = wbuf;
        }
        lbar();
        {   // crossing partials: wave wv covers k-slice [wv*64, wv*64+64)
            int r = lane>>1, col = lane&1;
            const unsigned char* hp = &abuf[hb][r][wv*64];
            const float* wp = &smallw[col*512 + wv*64];
            float p = 0.f;
            #pragma unroll
            for (int k4=0;k4<16;++k4){
                int v = *(const int*)(hp + k4*4);
                p += (float)((signed char)(v    )) * wp[k4*4+0];
                p += (float)((signed char)(v>>8 )) * wp[k4*4+1];
                p += (float)((signed char)(v>>16)) * wp[k4*4+2];
                p += (float)((signed char)(v>>24)) * wp[k4*4+3];
            }
            partial[wv*64 + lane] = p;
        }
        lbar();
        if (wv == 0) {
            float p = 0.f;
            #pragma unroll
            for (int i=0;i<8;++i) p += partial[i*64 + lane];
            int r = lane>>1, col = lane&1;
            p = p*(1.f/127.f) + smallw[1024+col];
            float cr = fmaxf(p, 0.f);
            float other = __shfl_xor(cr, 1, 64);
            float mx = fmaxf(cr, other);
            float e0 = ex2(LOG2E*(cr-mx)), e1 = ex2(LOG2E*(other-mx));
            out[((size_t)(row0+r))*32 + t*2 + col] = e0*rcpn(e0+e1);
            float c0v = col ? other : cr;
            float c1v = col ? cr : other;
            #pragma unroll
            for (int q2=0;q2<2;++q2){
                int e = col*2 + q2;
                float lp = fmaxf(c0v*smallw[1026+e*2] + c1v*smallw[1026+e*2+1] + smallw[1034+e], 0.f);
                int qv = (int)rintf(fminf(lp*31.75f, 127.f));
                unsigned char qb = (unsigned char)qv;
                abuf[hb][r][512+e]=qb; abuf[hb][r][516+e]=qb; abuf[hb][r][520+e]=qb; abuf[hb][r][524+e]=qb;
            }
        }
        lbar();
    }
}

extern "C" void kernel_launch(void* const* d_in, const int* in_sizes, int n_in,
                              void* d_out, int out_size, void* d_ws, size_t ws_size,
                              hipStream_t stream)
{
    (void)in_sizes; (void)n_in; (void)out_size; (void)ws_size;
    const float* speed = (const float*)d_in[0];
    const float* pos   = (const float*)d_in[1];
    const float* Ws_ih = (const float*)d_in[2];
    const float* Ws_hh = (const float*)d_in[3];
    const float* bs_ih = (const float*)d_in[4];
    const float* bs_hh = (const float*)d_in[5];
    const float* Wp_ih = (const float*)d_in[6];
    const float* Wp_hh = (const float*)d_in[7];
    const float* bp_ih = (const float*)d_in[8];
    const float* bp_hh = (const float*)d_in[9];
    const float* Wd_ih = (const float*)d_in[10];
    const float* Wd_hh = (const float*)d_in[11];
    const float* bd_ih = (const float*)d_in[12];
    const float* bd_hh = (const float*)d_in[13];
    const float* W_fc  = (const float*)d_in[14];
    const float* b_fc  = (const float*)d_in[15];
    const float* W_emb = (const float*)d_in[16];
    const float* b_emb = (const float*)d_in[17];

    unsigned char* wp8 = (unsigned char*)d_ws;
    int*   smax  = (int*)(wp8 + 3*(size_t)LSTR);
    float* gsout = (float*)(wp8 + 3*(size_t)LSTR + 16);

    scale_k<<<96, 256, 0, stream>>>(Ws_ih,Ws_hh,bs_ih,bs_hh, Wp_ih,Wp_hh,bp_ih,bp_hh,
                                    Wd_ih,Wd_hh,bd_ih,bd_hh, smax);
    int gb = (LSTR/4 + 255) / 256;
    pack_k<<<gb, 256, 0, stream>>>(Ws_ih, Ws_hh, bs_ih, bs_hh, smax, 0, wp8,                  gsout);
    pack_k<<<gb, 256, 0, stream>>>(Wp_ih, Wp_hh, bp_ih, bp_hh, smax, 1, wp8 +   (size_t)LSTR, gsout);
    pack_k<<<gb, 256, 0, stream>>>(Wd_ih, Wd_hh, bd_ih, bd_hh, smax, 2, wp8 + 2*(size_t)LSTR, gsout);
    lstm_all<<<NBLK, NTHR, 0, stream>>>(speed, pos, wp8, gsout,
                                        W_fc, b_fc, W_emb, b_emb, (float*)d_out);
}